// Round 5
// baseline (194.447 us; speedup 1.0000x reference)
//
#include <hip/hip_runtime.h>
#include <hip/hip_bf16.h>
#include <stdint.h>

typedef unsigned short ushort_t;
typedef short v8s __attribute__((ext_vector_type(8)));
typedef float f32x4 __attribute__((ext_vector_type(4)));
typedef float f32x16 __attribute__((ext_vector_type(16)));

#define MFMA16(a, b, c) __builtin_amdgcn_mfma_f32_16x16x32_bf16(a, b, c, 0, 0, 0)
#define MFMA32(a, b, c) __builtin_amdgcn_mfma_f32_32x32x16_bf16(a, b, c, 0, 0, 0)

__device__ __forceinline__ ushort_t f2bf(float f) {
    union { __hip_bfloat16 b; ushort_t u; } c;
    c.b = __float2bfloat16(f);
    return c.u;
}

__device__ __forceinline__ unsigned f2bf2(float a, float b) {
    union { __hip_bfloat162 b2; unsigned u; } c;
    c.b2 = __float22bfloat162_rn(make_float2(a, b));
    return c.u;
}

// ---------------------------------------------------------------------------
// Kernel 1: transpose W [2048][128] f32 -> WT [384][2048] bf16 (q|k|v rows)
// ---------------------------------------------------------------------------
__global__ void transpose_w(const float* __restrict__ Wq, const float* __restrict__ Wk,
                            const float* __restrict__ Wv, ushort_t* __restrict__ WT) {
    __shared__ float tile[64][132];
    int bid = blockIdx.x;            // 96 = 3 weights x 32 k-blocks
    int w = bid >> 5;
    int k0 = (bid & 31) << 6;
    const float* W = (w == 0) ? Wq : ((w == 1) ? Wk : Wv);
    int tid = threadIdx.x;
    #pragma unroll
    for (int i = 0; i < 8; i++) {
        int row = i * 8 + (tid >> 5);
        int col = (tid & 31) * 4;
        float4 v = *(const float4*)(W + (size_t)(k0 + row) * 128 + col);
        tile[row][col] = v.x; tile[row][col + 1] = v.y;
        tile[row][col + 2] = v.z; tile[row][col + 3] = v.w;
    }
    __syncthreads();
    int n = tid >> 1, kh = (tid & 1) * 32;
    ushort_t* dst = WT + ((size_t)(w * 128 + n)) * 2048 + k0 + kh;
    #pragma unroll
    for (int j = 0; j < 32; j += 4) {
        union { ushort_t u[4]; uint2 v2; } pk;
        #pragma unroll
        for (int e = 0; e < 4; e++) pk.u[e] = f2bf(tile[kh + j + e][n]);
        *(uint2*)(dst + j) = pk.v2;
    }
}

// ---------------------------------------------------------------------------
// Kernel 2: fused QKV projection — ZERO LDS, ZERO barriers (pure dataflow).
// Swapped MFMA orientation: out^T-tile = MFMA16(A = WT-frag, B = x-frag).
//   A: lane lr = w-col, 16B v8s straight from WT (L2-resident, 1.5 MB).
//   B: lane lr = x-row, 32B f32 (own row k-slice) -> cvt_pk -> v8s.
// Grid 512 = 256 mtiles(64 rows) x 2 nhalves(192 cols), XCD-paired so the
// pair shares one x fetch. 4 waves = 2(m) x 2(c); wave = 32m x 96c.
// BK=32, 64 iters; 2-deep ping-pong register prefetch for x and W.
// D-frag: value = out[t = base_m + lr][col = base_c + 4*lg + e].
// Blocked output layouts (per batch 524288 elems):
//   q_blk/k_blk: (t>>5)*4096 + (d>>4)*512 + ((d>>3)&1)*256 + (t&31)*8 + (d&7)
//   v_blk:       (t>>4)*2048 + (d>>5)*512 + ((t>>3)&1)*256 + (d&31)*8 + (t&7)
// ---------------------------------------------------------------------------
#define PJ_LOADX(XS, IT)                                                      \
    {                                                                         \
        _Pragma("unroll")                                                     \
        for (int mt = 0; mt < 2; mt++) {                                      \
            XS[2 * mt]     = *(const f32x4*)(xb[mt] + (size_t)(IT) * 128);    \
            XS[2 * mt + 1] = *(const f32x4*)(xb[mt] + (size_t)(IT) * 128 + 16); \
        }                                                                     \
    }

#define PJ_LOADW(WS, IT)                                                      \
    {                                                                         \
        _Pragma("unroll")                                                     \
        for (int n = 0; n < 6; n++)                                           \
            WS[n] = *(const v8s*)(wb[n] + (size_t)(IT) * 64);                 \
    }

#define PJ_STEP(XS, WS, IT, DOLOAD)                                           \
    {                                                                         \
        v8s xf[2];                                                            \
        _Pragma("unroll")                                                     \
        for (int mt = 0; mt < 2; mt++) {                                      \
            union { unsigned u[4]; v8s v; } pk;                               \
            pk.u[0] = f2bf2(XS[2 * mt][0], XS[2 * mt][1]);                    \
            pk.u[1] = f2bf2(XS[2 * mt][2], XS[2 * mt][3]);                    \
            pk.u[2] = f2bf2(XS[2 * mt + 1][0], XS[2 * mt + 1][1]);            \
            pk.u[3] = f2bf2(XS[2 * mt + 1][2], XS[2 * mt + 1][3]);            \
            xf[mt] = pk.v;                                                    \
        }                                                                     \
        if (DOLOAD) PJ_LOADX(XS, (IT) + 2);                                   \
        __builtin_amdgcn_s_setprio(1);                                        \
        _Pragma("unroll")                                                     \
        for (int m = 0; m < 2; m++)                                           \
            _Pragma("unroll")                                                 \
            for (int n = 0; n < 6; n++)                                       \
                acc[m][n] = MFMA16(WS[n], xf[m], acc[m][n]);                  \
        __builtin_amdgcn_s_setprio(0);                                        \
        if (DOLOAD) PJ_LOADW(WS, (IT) + 2);                                   \
    }

__launch_bounds__(256, 2)
__global__ void proj_kernel(const float* __restrict__ x, const ushort_t* __restrict__ WT,
                            ushort_t* __restrict__ q, ushort_t* __restrict__ kb,
                            ushort_t* __restrict__ vb) {
    int bid = blockIdx.x;
    int mt8 = bid & 7, nh = (bid >> 3) & 1, mg = bid >> 4;
    int mtile = mg * 8 + mt8;                 // (mtile,0)/(mtile,1) same XCD
    size_t m0 = (size_t)mtile * 64;
    int c0 = nh * 192;
    int tid = threadIdx.x, lane = tid & 63, wid = tid >> 6;
    int lg = lane >> 4, lr = lane & 15;
    int wr = wid >> 1, wc = wid & 1;

    f32x4 acc[2][6];
    #pragma unroll
    for (int m = 0; m < 2; m++)
        #pragma unroll
        for (int n = 0; n < 6; n++) acc[m][n] = (f32x4){0.f, 0.f, 0.f, 0.f};

    // per-lane global bases
    const char* xb[2];
    #pragma unroll
    for (int mt = 0; mt < 2; mt++)
        xb[mt] = (const char*)x + (m0 + wr * 32 + mt * 16 + lr) * 8192 + lg * 32;
    const char* wb[6];
    #pragma unroll
    for (int n = 0; n < 6; n++)
        wb[n] = (const char*)WT + (size_t)(c0 + wc * 96 + n * 16 + lr) * 4096 + lg * 16;

    f32x4 xs0[4], xs1[4];
    v8s wt0[6], wt1[6];

    // prologue: prefetch iters 0 and 1
    PJ_LOADX(xs0, 0); PJ_LOADW(wt0, 0);
    PJ_LOADX(xs1, 1); PJ_LOADW(wt1, 1);

    for (int it = 0; it < 60; it += 2) {
        PJ_STEP(xs0, wt0, it, 1);
        PJ_STEP(xs1, wt1, it + 1, 1);
    }
    PJ_STEP(xs0, wt0, 60, 1);
    PJ_STEP(xs1, wt1, 61, 1);
    PJ_STEP(xs0, wt0, 62, 0);
    PJ_STEP(xs1, wt1, 63, 0);

    // epilogue: lane value = out[t][col], t = m-row (lr), col = 4*lg+e slice
    #pragma unroll
    for (int m = 0; m < 2; m++) {
        size_t t = m0 + (size_t)(wr * 32 + m * 16 + lr);
        size_t base = (t >> 12) * 524288;
        int tt = (int)(t & 4095);
        size_t tq = base + (size_t)(tt >> 5) * 4096 + (tt & 31) * 8;
        size_t tv = base + (size_t)(tt >> 4) * 2048 + ((tt >> 3) & 1) * 256 + (tt & 7);
        #pragma unroll
        for (int n = 0; n < 6; n++) {
            int col = c0 + wc * 96 + n * 16 + 4 * lg;
            int w = col >> 7, d = col & 127;
            if (w < 2) {
                ushort_t* dst = (w == 0) ? q : kb;
                size_t off = tq + (size_t)(d >> 4) * 512 + ((d >> 3) & 1) * 256 + (d & 7);
                uint2 pv;
                pv.x = f2bf2(acc[m][n][0], acc[m][n][1]);
                pv.y = f2bf2(acc[m][n][2], acc[m][n][3]);
                *(uint2*)(dst + off) = pv;
            } else {
                #pragma unroll
                for (int e = 0; e < 4; e++) {
                    int dd = d + e;
                    vb[tv + (size_t)(dd >> 5) * 512 + (dd & 31) * 8] = f2bf(acc[m][n][e]);
                }
            }
        }
    }
}

// ---------------------------------------------------------------------------
// Kernel 3: causal flash attention, 32x32 MFMA, swapped QK^T (S^T = K·Q^T),
// O^T = V^T·P^T. 512 blocks (b, qtile of 32 rows) x 4 waves; waves split KV
// tiles mod 4, merge 4 partial (m,l,O) states via LDS at the end. No LDS or
// barriers in the hot loop. V-frags as rolling 2-ahead pair + P-pack folded
// into the PV loop: peak ~190 VGPR -> 2 waves/SIMD without spill.
// ---------------------------------------------------------------------------
__device__ __forceinline__ f32x16 zero16() {
    f32x16 z;
    #pragma unroll
    for (int i = 0; i < 16; i++) z[i] = 0.f;
    return z;
}

#define ATT_PVC(SV, BASE, VC, CNEXT)                                          \
    {                                                                         \
        unsigned a0 = f2bf2(SV[(BASE) + 0], SV[(BASE) + 1]);                  \
        unsigned a1 = f2bf2(SV[(BASE) + 2], SV[(BASE) + 3]);                  \
        unsigned b0 = f2bf2(SV[(BASE) + 4], SV[(BASE) + 5]);                  \
        unsigned b1 = f2bf2(SV[(BASE) + 6], SV[(BASE) + 7]);                  \
        unsigned snd0 = hi ? a0 : b0, snd1 = hi ? a1 : b1;                    \
        unsigned rcv0 = (unsigned)__shfl_xor((int)snd0, 32);                  \
        unsigned rcv1 = (unsigned)__shfl_xor((int)snd1, 32);                  \
        union { unsigned u[4]; v8s v; } pf;                                   \
        pf.u[0] = hi ? rcv0 : a0;                                             \
        pf.u[1] = hi ? rcv1 : a1;                                             \
        pf.u[2] = hi ? b0 : rcv0;                                             \
        pf.u[3] = hi ? b1 : rcv1;                                             \
        __builtin_amdgcn_s_setprio(1);                                        \
        _Pragma("unroll")                                                     \
        for (int dt = 0; dt < 4; dt++)                                        \
            accO[dt] = MFMA32(VC[dt], pf.v, accO[dt]);                        \
        __builtin_amdgcn_s_setprio(0);                                        \
        if ((CNEXT) >= 0) {                                                   \
            _Pragma("unroll")                                                 \
            for (int dt = 0; dt < 4; dt++)                                    \
                VC[dt] = *(const v8s*)(vg + (CNEXT) * 2048 + dt * 512);       \
        }                                                                     \
    }

__launch_bounds__(256, 2)
__global__ void attn_kernel(const ushort_t* __restrict__ q, const ushort_t* __restrict__ kb,
                            const ushort_t* __restrict__ vb, float* __restrict__ out) {
    __shared__ float obuf[4][4][16][64];   // [srcwave][dt][r][lane]  64 KB
    __shared__ float stat[2][4][64];       // m, l per wave per lane

    int bid = blockIdx.x;
    int xcd = bid & 7, rk = bid >> 3;
    int b = xcd >> 1;                       // batch pinned to XCD pair
    int g = rk * 2 + (xcd & 1);             // 0..127
    int qt = (g & 1) ? (g >> 1) : (127 - (g >> 1));   // alternate long/short
    int qt0 = qt * 32;
    int tid = threadIdx.x, lane = tid & 63, wid = tid >> 6;
    int hi = lane >> 5, lo = lane & 31;
    size_t bb = (size_t)b * 524288;
    int nt = (qt >> 1) + 1;
    const float cexp = 0.08838834764831845f * 1.4426950408889634f;  // scale*log2e

    // Q fragments (B-operand): lane holds Q[qt0+lo][ks*16+hi*8+j]
    v8s qf[8];
    {
        const ushort_t* qg = q + bb + (size_t)qt * 4096 + (size_t)lane * 8;
        #pragma unroll
        for (int ks = 0; ks < 8; ks++) qf[ks] = *(const v8s*)(qg + ks * 512);
    }

    f32x16 accO[4];
    #pragma unroll
    for (int dt = 0; dt < 4; dt++) accO[dt] = zero16();
    float mrun = -1e30f, lrun = 0.f;

    for (int t = wid; t < nt; t += 4) {
        const ushort_t* kg = kb + bb + (size_t)t * 8192 + (size_t)lane * 8;
        const ushort_t* vg = vb + bb + (size_t)t * 8192 + (size_t)lane * 8;

        // S^T = K·Q^T : two 32-kv subtiles, K-loop over d (8 steps of 16)
        f32x16 s0 = zero16(), s1 = zero16();
        __builtin_amdgcn_s_setprio(1);
        #pragma unroll
        for (int ks = 0; ks < 8; ks++) {
            v8s kf = *(const v8s*)(kg + ks * 512);
            s0 = MFMA32(kf, qf[ks], s0);
        }
        #pragma unroll
        for (int ks = 0; ks < 8; ks++) {
            v8s kf = *(const v8s*)(kg + 4096 + ks * 512);
            s1 = MFMA32(kf, qf[ks], s1);
        }
        __builtin_amdgcn_s_setprio(0);

        // V-frag rolling pair: c=0 and c=1 issued here, latency hidden by
        // the mask + softmax VALU below.
        v8s vA[4], vB[4];
        #pragma unroll
        for (int dt = 0; dt < 4; dt++) vA[dt] = *(const v8s*)(vg + dt * 512);
        #pragma unroll
        for (int dt = 0; dt < 4; dt++) vB[dt] = *(const v8s*)(vg + 2048 + dt * 512);

        // causal mask (diagonal tile only); S^T row index kv=(r&3)+8*(r>>2)+4*hi
        if (t == nt - 1) {
            int qrow = qt0 + lo;
            #pragma unroll
            for (int r = 0; r < 16; r++) {
                int kvb = t * 64 + (r & 3) + 8 * (r >> 2) + 4 * hi;
                if (kvb > qrow) s0[r] = -1e30f;
                if (kvb + 32 > qrow) s1[r] = -1e30f;
            }
        }

        // online softmax: lane owns q-row lo; only cross-lane op is xor-32
        float mx = s0[0];
        #pragma unroll
        for (int r = 1; r < 16; r++) mx = fmaxf(mx, s0[r]);
        #pragma unroll
        for (int r = 0; r < 16; r++) mx = fmaxf(mx, s1[r]);
        mx = fmaxf(mx, __shfl_xor(mx, 32));

        if (__any(mx > mrun + 62.7f)) {     // defer-max: skip rescale if growth < 8/cexp
            float mnew = fmaxf(mrun, mx);
            float fr = exp2f((mrun - mnew) * cexp);
            lrun *= fr;
            #pragma unroll
            for (int dt = 0; dt < 4; dt++)
                #pragma unroll
                for (int r = 0; r < 16; r++) accO[dt][r] *= fr;
            mrun = mnew;
        }
        float mc = mrun * cexp;
        float rs = 0.f;
        #pragma unroll
        for (int r = 0; r < 16; r++) { s0[r] = exp2f(fmaf(s0[r], cexp, -mc)); rs += s0[r]; }
        #pragma unroll
        for (int r = 0; r < 16; r++) { s1[r] = exp2f(fmaf(s1[r], cexp, -mc)); rs += s1[r]; }
        rs += __shfl_xor(rs, 32);
        lrun += rs;

        // PV: O^T += V^T·P^T ; P-frag assembled in-loop (1 shfl pair / chunk),
        // V-frags prefetched 2 chunks ahead into the just-consumed set.
        ATT_PVC(s0, 0, vA, 2);
        ATT_PVC(s0, 8, vB, 3);
        ATT_PVC(s1, 0, vA, -1);
        ATT_PVC(s1, 8, vB, -1);
    }

    // ---- merge the 4 waves' partial (m, l, O^T) states ----
    #pragma unroll
    for (int dt = 0; dt < 4; dt++)
        #pragma unroll
        for (int r = 0; r < 16; r++)
            obuf[wid][dt][r][lane] = accO[dt][r];
    stat[0][wid][lane] = mrun;
    stat[1][wid][lane] = lrun;
    __syncthreads();

    float m0 = stat[0][0][lane], m1 = stat[0][1][lane];
    float m2 = stat[0][2][lane], m3 = stat[0][3][lane];
    float m = fmaxf(fmaxf(m0, m1), fmaxf(m2, m3));
    float f0 = exp2f((m0 - m) * cexp), f1 = exp2f((m1 - m) * cexp);
    float f2 = exp2f((m2 - m) * cexp), f3 = exp2f((m3 - m) * cexp);
    float lsum = f0 * stat[1][0][lane] + f1 * stat[1][1][lane]
               + f2 * stat[1][2][lane] + f3 * stat[1][3][lane];
    float linv = 1.0f / lsum;

    float o[16];
    #pragma unroll
    for (int r = 0; r < 16; r++)
        o[r] = (f0 * obuf[0][wid][r][lane] + f1 * obuf[1][wid][r][lane]
              + f2 * obuf[2][wid][r][lane] + f3 * obuf[3][wid][r][lane]) * linv;

    // wave wid owns output cols wid*32..+32; col = wid*32 + 8a + 4hi + e
    float* orow = out + ((size_t)b * 4096 + qt0 + lo) * 128 + wid * 32 + 4 * hi;
    #pragma unroll
    for (int a = 0; a < 4; a++) {
        float4 vv;
        vv.x = o[4 * a + 0]; vv.y = o[4 * a + 1];
        vv.z = o[4 * a + 2]; vv.w = o[4 * a + 3];
        *(float4*)(orow + 8 * a) = vv;
    }
}

// ---------------------------------------------------------------------------
extern "C" void kernel_launch(void* const* d_in, const int* in_sizes, int n_in,
                              void* d_out, int out_size, void* d_ws, size_t ws_size,
                              hipStream_t stream) {
    const float* x  = (const float*)d_in[0];
    const float* Wq = (const float*)d_in[1];
    const float* Wk = (const float*)d_in[2];
    const float* Wv = (const float*)d_in[3];
    float* out = (float*)d_out;
    char* ws = (char*)d_ws;

    ushort_t* q  = (ushort_t*)(ws);               // 4 MB  q_blk
    ushort_t* kb = (ushort_t*)(ws + (4u << 20));  // 4 MB  k_blk
    ushort_t* vb = (ushort_t*)(ws + (8u << 20));  // 4 MB  v_blk
    ushort_t* WT = (ushort_t*)(ws + (12u << 20)); // 1.5MB WT bf16 [384][2048]

    transpose_w<<<dim3(96), dim3(256), 0, stream>>>(Wq, Wk, Wv, WT);
    proj_kernel<<<dim3(512), dim3(256), 0, stream>>>(x, WT, q, kb, vb);
    attn_kernel<<<dim3(512), dim3(256), 0, stream>>>(q, kb, vb, out);
}

// Round 6
// 98.801 us; speedup vs baseline: 1.9681x; 1.9681x over previous
//
#include <hip/hip_runtime.h>
#include <hip/hip_bf16.h>
#include <stdint.h>

typedef unsigned short ushort_t;
typedef short v8s __attribute__((ext_vector_type(8)));
typedef float f32x4 __attribute__((ext_vector_type(4)));
typedef float f32x16 __attribute__((ext_vector_type(16)));

#define MFMA16(a, b, c) __builtin_amdgcn_mfma_f32_16x16x32_bf16(a, b, c, 0, 0, 0)
#define MFMA32(a, b, c) __builtin_amdgcn_mfma_f32_32x32x16_bf16(a, b, c, 0, 0, 0)

typedef __attribute__((address_space(1))) void gvoid;
typedef __attribute__((address_space(3))) void svoid;

__device__ __forceinline__ void gld16(const void* g, void* s) {
    __builtin_amdgcn_global_load_lds((gvoid*)g, (svoid*)s, 16, 0, 0);
}

__device__ __forceinline__ ushort_t f2bf(float f) {
    union { __hip_bfloat16 b; ushort_t u; } c;
    c.b = __float2bfloat16(f);
    return c.u;
}

__device__ __forceinline__ unsigned f2bf2(float a, float b) {
    union { __hip_bfloat162 b2; unsigned u; } c;
    c.b2 = __float22bfloat162_rn(make_float2(a, b));
    return c.u;
}

// ---------------------------------------------------------------------------
// Kernel 1: transpose W [2048][128] f32 -> WT [384][2048] bf16 (q|k|v rows)
// ---------------------------------------------------------------------------
__global__ void transpose_w(const float* __restrict__ Wq, const float* __restrict__ Wk,
                            const float* __restrict__ Wv, ushort_t* __restrict__ WT) {
    __shared__ float tile[64][132];
    int bid = blockIdx.x;            // 96 = 3 weights x 32 k-blocks
    int w = bid >> 5;
    int k0 = (bid & 31) << 6;
    const float* W = (w == 0) ? Wq : ((w == 1) ? Wk : Wv);
    int tid = threadIdx.x;
    #pragma unroll
    for (int i = 0; i < 8; i++) {
        int row = i * 8 + (tid >> 5);
        int col = (tid & 31) * 4;
        float4 v = *(const float4*)(W + (size_t)(k0 + row) * 128 + col);
        tile[row][col] = v.x; tile[row][col + 1] = v.y;
        tile[row][col + 2] = v.z; tile[row][col + 3] = v.w;
    }
    __syncthreads();
    int n = tid >> 1, kh = (tid & 1) * 32;
    ushort_t* dst = WT + ((size_t)(w * 128 + n)) * 2048 + k0 + kh;
    #pragma unroll
    for (int j = 0; j < 32; j += 4) {
        union { ushort_t u[4]; uint2 v2; } pk;
        #pragma unroll
        for (int e = 0; e < 4; e++) pk.u[e] = f2bf(tile[kh + j + e][n]);
        *(uint2*)(dst + j) = pk.v2;
    }
}

// ---------------------------------------------------------------------------
// Kernel 2: fused QKV projection (R3 structure + counted vmcnt + XCD pairing).
// grid 512 = 256 mtiles(64 rows) x 2 nhalves(192 cols); (mt,0)/(mt,1) differ
// by 8 in blockIdx -> same XCD (bid%8) -> x tile fetched once from HBM.
// 4 waves; wave = 64m x 48c (acc[4][3]); BK=64, 32 iters.
// A: x 2-iters-ahead in ping-pong regs -> cvt_pk -> ds_write 1 ahead.
// B: gld16 1 tile ahead, pre-swizzled source.
// Steady-state barrier: vmcnt(4) (x(it+2) stays in flight) + lgkmcnt(0).
// Blocked output layouts (per batch 524288 elems):
//   q_blk/k_blk: (t>>5)*4096 + (d>>4)*512 + ((d>>3)&1)*256 + (t&31)*8 + (d&7)
//   v_blk:       (t>>4)*2048 + (d>>5)*512 + ((t>>3)&1)*256 + (d&31)*8 + (t&7)
// ---------------------------------------------------------------------------
#define PROJ_CVT_WRITE(RS, CUR)                                               \
    {                                                                         \
        union { unsigned u[4]; v8s v; } p0, p1;                               \
        p0.u[0] = f2bf2(RS[0][0], RS[0][1]); p0.u[1] = f2bf2(RS[0][2], RS[0][3]); \
        p0.u[2] = f2bf2(RS[1][0], RS[1][1]); p0.u[3] = f2bf2(RS[1][2], RS[1][3]); \
        p1.u[0] = f2bf2(RS[2][0], RS[2][1]); p1.u[1] = f2bf2(RS[2][2], RS[2][3]); \
        p1.u[2] = f2bf2(RS[3][0], RS[3][1]); p1.u[3] = f2bf2(RS[3][2], RS[3][3]); \
        *(v8s*)((char*)abuf + ((CUR) ^ 1) * 8192 + awb0) = p0.v;              \
        *(v8s*)((char*)abuf + ((CUR) ^ 1) * 8192 + awb1) = p1.v;              \
    }

#define PJ_STEP(IT, RLOAD, RCVT, DOX, DOB)                                    \
    {                                                                         \
        const int cur = (IT) & 1;                                             \
        if (DOB) {                                                            \
            _Pragma("unroll")                                                 \
            for (int i = 0; i < 6; i++)                                       \
                gld16(bsrc[i] + (size_t)((IT) + 1) * 128,                     \
                      (char*)bbuf + (cur ^ 1) * 24576 + (wid * 6 + i) * 1024);\
        }                                                                     \
        __builtin_amdgcn_sched_barrier(0);                                    \
        if (DOX) {                                                            \
            _Pragma("unroll")                                                 \
            for (int c = 0; c < 4; c++)                                       \
                RLOAD[c] = *(const f32x4*)(xp + (size_t)((IT) + 2) * 256 + c * 16); \
        }                                                                     \
        __builtin_amdgcn_sched_barrier(0);                                    \
        const char* ab = (const char*)abuf + cur * 8192;                      \
        const char* bb = (const char*)bbuf + cur * 24576;                     \
        _Pragma("unroll")                                                     \
        for (int kk = 0; kk < 2; kk++) {                                      \
            v8s af[4], bf[3];                                                 \
            _Pragma("unroll")                                                 \
            for (int m = 0; m < 4; m++) {                                     \
                int row = m * 16 + lr;                                        \
                af[m] = *(const v8s*)(ab + row * 128 +                        \
                         ((kk * 64 + lg * 16) ^ ((row & 7) << 4)));           \
            }                                                                 \
            _Pragma("unroll")                                                 \
            for (int n = 0; n < 3; n++) {                                     \
                int row = wid * 48 + n * 16 + lr;                             \
                bf[n] = *(const v8s*)(bb + row * 128 +                        \
                         ((kk * 64 + lg * 16) ^ ((row & 7) << 4)));           \
            }                                                                 \
            __builtin_amdgcn_s_setprio(1);                                    \
            _Pragma("unroll")                                                 \
            for (int m = 0; m < 4; m++)                                       \
                _Pragma("unroll")                                             \
                for (int n = 0; n < 3; n++)                                   \
                    acc[m][n] = MFMA16(af[m], bf[n], acc[m][n]);              \
            __builtin_amdgcn_s_setprio(0);                                    \
        }                                                                     \
        if (DOB) PROJ_CVT_WRITE(RCVT, cur);                                   \
        __builtin_amdgcn_sched_barrier(0);                                    \
        if (DOB) {                                                            \
            if (DOX) { asm volatile("s_waitcnt vmcnt(4)" ::: "memory"); }     \
            else     { asm volatile("s_waitcnt vmcnt(0)" ::: "memory"); }     \
            asm volatile("s_waitcnt lgkmcnt(0)" ::: "memory");                \
            __builtin_amdgcn_s_barrier();                                     \
        }                                                                     \
        __builtin_amdgcn_sched_barrier(0);                                    \
    }

__launch_bounds__(256, 2)
__global__ void proj_kernel(const float* __restrict__ x, const ushort_t* __restrict__ WT,
                            ushort_t* __restrict__ q, ushort_t* __restrict__ kb,
                            ushort_t* __restrict__ vb) {
    __shared__ ushort_t abuf[2][4096];    // [64 m][64 k] bf16, byte ^ ((row&7)<<4)
    __shared__ ushort_t bbuf[2][12288];   // [192 n][64 k] bf16, same swizzle

    int bid = blockIdx.x;
    int mt8 = bid & 7, nh = (bid >> 3) & 1, mg = bid >> 4;
    int mtile = mg * 8 + mt8;             // (mtile,0)/(mtile,1): bids differ by 8
    size_t m0 = (size_t)mtile * 64;
    int c0 = nh * 192;
    int tid = threadIdx.x, lane = tid & 63, wid = tid >> 6;
    int lg = lane >> 4, lr = lane & 15;

    f32x4 acc[4][3];
    #pragma unroll
    for (int m = 0; m < 4; m++)
        #pragma unroll
        for (int n = 0; n < 3; n++) acc[m][n] = (f32x4){0.f, 0.f, 0.f, 0.f};

    // A-loads: wave stages rows 16*wid..+15; lane -> row 16wid+(lane>>2),
    // 64 contiguous bytes at (lane&3)*64 within the row's 256B k-chunk.
    int ar = 16 * wid + (lane >> 2);
    const char* xp = (const char*)x + (m0 + ar) * 8192 + (lane & 3) * 64;
    int aswz = (ar & 7) << 4;
    int awb0 = ar * 128 + (((lane & 3) * 32 + 0) ^ aswz);
    int awb1 = ar * 128 + (((lane & 3) * 32 + 16) ^ aswz);

    // B stage: wave's 6 segs = exactly the 48 rows it reads.
    const char* bsrc[6];
    #pragma unroll
    for (int i = 0; i < 6; i++) {
        int row = 8 * (wid * 6 + i) + (lane >> 3);
        int col = ((lane & 7) * 16) ^ ((row & 7) << 4);
        bsrc[i] = (const char*)WT + (size_t)(c0 + row) * 4096 + col;
    }

    f32x4 s0[4], s1[4];
    // ---- prologue: B(0) gld16, x(0)->s0, x(1)->s1, cvt A(0) ----
    #pragma unroll
    for (int i = 0; i < 6; i++)
        gld16(bsrc[i], (char*)bbuf + (wid * 6 + i) * 1024);
    #pragma unroll
    for (int c = 0; c < 4; c++) s0[c] = *(const f32x4*)(xp + c * 16);
    #pragma unroll
    for (int c = 0; c < 4; c++) s1[c] = *(const f32x4*)(xp + 256 + c * 16);
    PROJ_CVT_WRITE(s0, 1);   // waits x(0) (=> B(0) too, FIFO); writes abuf[0]
    asm volatile("s_waitcnt lgkmcnt(0)" ::: "memory");
    __builtin_amdgcn_s_barrier();

    // x(n) lives in set n%2: load x(it+2) -> set it%2, cvt x(it+1) from (it+1)%2
    for (int it2 = 0; it2 < 30; it2 += 2) {
        PJ_STEP(it2,     s0, s1, 1, 1);
        PJ_STEP(it2 + 1, s1, s0, 1, 1);
    }
    PJ_STEP(30, s0, s1, 0, 1);   // no x issue; vmcnt(0); cvt x(31)=s1
    PJ_STEP(31, s1, s0, 0, 0);   // compute only

    // epilogue: D-frag lane holds row = 4*lg+e, col = lr within each 16x16 tile
    #pragma unroll
    for (int m = 0; m < 4; m++) {
        #pragma unroll
        for (int e = 0; e < 4; e++) {
            size_t row = m0 + (size_t)(m * 16 + 4 * lg + e);
            int t = (int)(row & 4095);
            size_t base = (row >> 12) * 524288;
            #pragma unroll
            for (int n = 0; n < 3; n++) {
                int col = c0 + wid * 48 + n * 16 + lr;
                int w = col >> 7, d = col & 127;
                ushort_t val = f2bf(acc[m][n][e]);
                if (w == 0)
                    q[base + (size_t)(t >> 5) * 4096 + (d >> 4) * 512 + ((d >> 3) & 1) * 256 + (t & 31) * 8 + (d & 7)] = val;
                else if (w == 1)
                    kb[base + (size_t)(t >> 5) * 4096 + (d >> 4) * 512 + ((d >> 3) & 1) * 256 + (t & 31) * 8 + (d & 7)] = val;
                else
                    vb[base + (size_t)(t >> 4) * 2048 + (d >> 5) * 512 + ((t >> 3) & 1) * 256 + (d & 31) * 8 + (t & 7)] = val;
            }
        }
    }
}

// ---------------------------------------------------------------------------
// Kernel 3: causal flash attention (UNCHANGED from R5 — measured ~26 µs).
// 32x32 MFMA, swapped QK^T (S^T = K·Q^T), O^T = V^T·P^T. 512 blocks x 4
// waves; waves split KV tiles mod 4, merge partials via LDS at the end.
// ---------------------------------------------------------------------------
__device__ __forceinline__ f32x16 zero16() {
    f32x16 z;
    #pragma unroll
    for (int i = 0; i < 16; i++) z[i] = 0.f;
    return z;
}

#define ATT_PVC(SV, BASE, VC, CNEXT)                                          \
    {                                                                         \
        unsigned a0 = f2bf2(SV[(BASE) + 0], SV[(BASE) + 1]);                  \
        unsigned a1 = f2bf2(SV[(BASE) + 2], SV[(BASE) + 3]);                  \
        unsigned b0 = f2bf2(SV[(BASE) + 4], SV[(BASE) + 5]);                  \
        unsigned b1 = f2bf2(SV[(BASE) + 6], SV[(BASE) + 7]);                  \
        unsigned snd0 = hi ? a0 : b0, snd1 = hi ? a1 : b1;                    \
        unsigned rcv0 = (unsigned)__shfl_xor((int)snd0, 32);                  \
        unsigned rcv1 = (unsigned)__shfl_xor((int)snd1, 32);                  \
        union { unsigned u[4]; v8s v; } pf;                                   \
        pf.u[0] = hi ? rcv0 : a0;                                             \
        pf.u[1] = hi ? rcv1 : a1;                                             \
        pf.u[2] = hi ? b0 : rcv0;                                             \
        pf.u[3] = hi ? b1 : rcv1;                                             \
        __builtin_amdgcn_s_setprio(1);                                        \
        _Pragma("unroll")                                                     \
        for (int dt = 0; dt < 4; dt++)                                        \
            accO[dt] = MFMA32(VC[dt], pf.v, accO[dt]);                        \
        __builtin_amdgcn_s_setprio(0);                                        \
        if ((CNEXT) >= 0) {                                                   \
            _Pragma("unroll")                                                 \
            for (int dt = 0; dt < 4; dt++)                                    \
                VC[dt] = *(const v8s*)(vg + (CNEXT) * 2048 + dt * 512);       \
        }                                                                     \
    }

__launch_bounds__(256, 2)
__global__ void attn_kernel(const ushort_t* __restrict__ q, const ushort_t* __restrict__ kb,
                            const ushort_t* __restrict__ vb, float* __restrict__ out) {
    __shared__ float obuf[4][4][16][64];   // [srcwave][dt][r][lane]  64 KB
    __shared__ float stat[2][4][64];       // m, l per wave per lane

    int bid = blockIdx.x;
    int xcd = bid & 7, rk = bid >> 3;
    int b = xcd >> 1;                       // batch pinned to XCD pair
    int g = rk * 2 + (xcd & 1);             // 0..127
    int qt = (g & 1) ? (g >> 1) : (127 - (g >> 1));   // alternate long/short
    int qt0 = qt * 32;
    int tid = threadIdx.x, lane = tid & 63, wid = tid >> 6;
    int hi = lane >> 5, lo = lane & 31;
    size_t bb = (size_t)b * 524288;
    int nt = (qt >> 1) + 1;
    const float cexp = 0.08838834764831845f * 1.4426950408889634f;  // scale*log2e

    // Q fragments (B-operand): lane holds Q[qt0+lo][ks*16+hi*8+j]
    v8s qf[8];
    {
        const ushort_t* qg = q + bb + (size_t)qt * 4096 + (size_t)lane * 8;
        #pragma unroll
        for (int ks = 0; ks < 8; ks++) qf[ks] = *(const v8s*)(qg + ks * 512);
    }

    f32x16 accO[4];
    #pragma unroll
    for (int dt = 0; dt < 4; dt++) accO[dt] = zero16();
    float mrun = -1e30f, lrun = 0.f;

    for (int t = wid; t < nt; t += 4) {
        const ushort_t* kg = kb + bb + (size_t)t * 8192 + (size_t)lane * 8;
        const ushort_t* vg = vb + bb + (size_t)t * 8192 + (size_t)lane * 8;

        // S^T = K·Q^T : two 32-kv subtiles, K-loop over d (8 steps of 16)
        f32x16 s0 = zero16(), s1 = zero16();
        __builtin_amdgcn_s_setprio(1);
        #pragma unroll
        for (int ks = 0; ks < 8; ks++) {
            v8s kf = *(const v8s*)(kg + ks * 512);
            s0 = MFMA32(kf, qf[ks], s0);
        }
        #pragma unroll
        for (int ks = 0; ks < 8; ks++) {
            v8s kf = *(const v8s*)(kg + 4096 + ks * 512);
            s1 = MFMA32(kf, qf[ks], s1);
        }
        __builtin_amdgcn_s_setprio(0);

        // V-frag rolling pair: c=0 and c=1 issued here, latency hidden by
        // the mask + softmax VALU below.
        v8s vA[4], vB[4];
        #pragma unroll
        for (int dt = 0; dt < 4; dt++) vA[dt] = *(const v8s*)(vg + dt * 512);
        #pragma unroll
        for (int dt = 0; dt < 4; dt++) vB[dt] = *(const v8s*)(vg + 2048 + dt * 512);

        // causal mask (diagonal tile only); S^T row index kv=(r&3)+8*(r>>2)+4*hi
        if (t == nt - 1) {
            int qrow = qt0 + lo;
            #pragma unroll
            for (int r = 0; r < 16; r++) {
                int kvb = t * 64 + (r & 3) + 8 * (r >> 2) + 4 * hi;
                if (kvb > qrow) s0[r] = -1e30f;
                if (kvb + 32 > qrow) s1[r] = -1e30f;
            }
        }

        // online softmax: lane owns q-row lo; only cross-lane op is xor-32
        float mx = s0[0];
        #pragma unroll
        for (int r = 1; r < 16; r++) mx = fmaxf(mx, s0[r]);
        #pragma unroll
        for (int r = 0; r < 16; r++) mx = fmaxf(mx, s1[r]);
        mx = fmaxf(mx, __shfl_xor(mx, 32));

        if (__any(mx > mrun + 62.7f)) {     // defer-max: skip rescale if growth < 8/cexp
            float mnew = fmaxf(mrun, mx);
            float fr = exp2f((mrun - mnew) * cexp);
            lrun *= fr;
            #pragma unroll
            for (int dt = 0; dt < 4; dt++)
                #pragma unroll
                for (int r = 0; r < 16; r++) accO[dt][r] *= fr;
            mrun = mnew;
        }
        float mc = mrun * cexp;
        float rs = 0.f;
        #pragma unroll
        for (int r = 0; r < 16; r++) { s0[r] = exp2f(fmaf(s0[r], cexp, -mc)); rs += s0[r]; }
        #pragma unroll
        for (int r = 0; r < 16; r++) { s1[r] = exp2f(fmaf(s1[r], cexp, -mc)); rs += s1[r]; }
        rs += __shfl_xor(rs, 32);
        lrun += rs;

        // PV: O^T += V^T·P^T ; P-frag assembled in-loop (1 shfl pair / chunk),
        // V-frags prefetched 2 chunks ahead into the just-consumed set.
        ATT_PVC(s0, 0, vA, 2);
        ATT_PVC(s0, 8, vB, 3);
        ATT_PVC(s1, 0, vA, -1);
        ATT_PVC(s1, 8, vB, -1);
    }

    // ---- merge the 4 waves' partial (m, l, O^T) states ----
    #pragma unroll
    for (int dt = 0; dt < 4; dt++)
        #pragma unroll
        for (int r = 0; r < 16; r++)
            obuf[wid][dt][r][lane] = accO[dt][r];
    stat[0][wid][lane] = mrun;
    stat[1][wid][lane] = lrun;
    __syncthreads();

    float m0 = stat[0][0][lane], m1 = stat[0][1][lane];
    float m2 = stat[0][2][lane], m3 = stat[0][3][lane];
    float m = fmaxf(fmaxf(m0, m1), fmaxf(m2, m3));
    float f0 = exp2f((m0 - m) * cexp), f1 = exp2f((m1 - m) * cexp);
    float f2 = exp2f((m2 - m) * cexp), f3 = exp2f((m3 - m) * cexp);
    float lsum = f0 * stat[1][0][lane] + f1 * stat[1][1][lane]
               + f2 * stat[1][2][lane] + f3 * stat[1][3][lane];
    float linv = 1.0f / lsum;

    float o[16];
    #pragma unroll
    for (int r = 0; r < 16; r++)
        o[r] = (f0 * obuf[0][wid][r][lane] + f1 * obuf[1][wid][r][lane]
              + f2 * obuf[2][wid][r][lane] + f3 * obuf[3][wid][r][lane]) * linv;

    // wave wid owns output cols wid*32..+32; col = wid*32 + 8a + 4hi + e
    float* orow = out + ((size_t)b * 4096 + qt0 + lo) * 128 + wid * 32 + 4 * hi;
    #pragma unroll
    for (int a = 0; a < 4; a++) {
        float4 vv;
        vv.x = o[4 * a + 0]; vv.y = o[4 * a + 1];
        vv.z = o[4 * a + 2]; vv.w = o[4 * a + 3];
        *(float4*)(orow + 8 * a) = vv;
    }
}

// ---------------------------------------------------------------------------
extern "C" void kernel_launch(void* const* d_in, const int* in_sizes, int n_in,
                              void* d_out, int out_size, void* d_ws, size_t ws_size,
                              hipStream_t stream) {
    const float* x  = (const float*)d_in[0];
    const float* Wq = (const float*)d_in[1];
    const float* Wk = (const float*)d_in[2];
    const float* Wv = (const float*)d_in[3];
    float* out = (float*)d_out;
    char* ws = (char*)d_ws;

    ushort_t* q  = (ushort_t*)(ws);               // 4 MB  q_blk
    ushort_t* kb = (ushort_t*)(ws + (4u << 20));  // 4 MB  k_blk
    ushort_t* vb = (ushort_t*)(ws + (8u << 20));  // 4 MB  v_blk
    ushort_t* WT = (ushort_t*)(ws + (12u << 20)); // 1.5MB WT bf16 [384][2048]

    transpose_w<<<dim3(96), dim3(256), 0, stream>>>(Wq, Wk, Wv, WT);
    proj_kernel<<<dim3(512), dim3(256), 0, stream>>>(x, WT, q, kb, vb);
    attn_kernel<<<dim3(512), dim3(256), 0, stream>>>(q, kb, vb, out);
}